// Round 9
// baseline (535.169 us; speedup 1.0000x reference)
//
#include <hip/hip_runtime.h>
#include <hip/hip_bf16.h>
#include <cstdint>

#define DI __device__ __forceinline__

typedef __attribute__((ext_vector_type(8))) short short8;
typedef __attribute__((ext_vector_type(4))) float f32x4;
typedef __attribute__((ext_vector_type(4))) int int4v;

DI f32x4 mfma16(short8 a, short8 b, f32x4 c) {
  return __builtin_amdgcn_mfma_f32_16x16x32_bf16(a, b, c, 0, 0, 0);
}

// fp32 -> bf16 round-to-nearest-even (bit trick, matches v_cvt rounding)
DI uint32_t f2bf(float f) {
  uint32_t u = __float_as_uint(f);
  return (u + 0x7fffu + ((u >> 16) & 1u)) >> 16;
}

DI uint32_t pk2(float a, float b) {
  return f2bf(a) | (f2bf(b) << 16);
}

DI short8 cvt8(float4 a, float4 b) {
  int4v t;
  t.x = (int)pk2(a.x, a.y);
  t.y = (int)pk2(a.z, a.w);
  t.z = (int)pk2(b.x, b.y);
  t.w = (int)pk2(b.z, b.w);
  return __builtin_bit_cast(short8, t);
}

// ---------------------------------------------------------------------------
// Gates GEMM, LDS-staged with wave-dense loads.
// Per block: 64 h-cols x 4 gates x K-chunk. Per K-step (BK=32 floats):
//   stage: W-tile 256 rows x 128 B (wave wv stages gate wv; 8 dwordx4/lane,
//          8 rows/instr fully-coalesced), A-tile 64 rows x 128 B (2/lane).
//   LDS layout: row-major, 16B-chunk XOR swizzle: chunk' = chunk ^ (row&7)
//   (conflict-free for both 8-lane/row writes and (l4,l15) fragment reads).
//   reg-carried double-buffer: load step s+1 into regs while computing s
//   from LDS; ds_write after the barrier (async-STAGE split).
// Chunk slots (blockIdx.y):
//   y in [0,40)  : x @ Wx0^T     (K=32000, 40 chunks x 25 steps)
//   y in [40,42) : h0 @ Wh[0]^T  (K=1024, 2 chunks x 16 steps)
//   y in [42,44) : h1 @ Wh[1]^T  (K=1024, 2 chunks x 16 steps)
__global__ __launch_bounds__(256, 3) void gates_f32(
    const float* __restrict__ x, const float* __restrict__ hs,
    const float* __restrict__ Wx0, const float* __restrict__ Wh,
    float* __restrict__ zpart) {
  __shared__ __align__(16) float lds[10240];  // W [0,8192), A [8192,10240)
  const int y = blockIdx.y;
  const float* A;
  const float* W;
  int ldA, K, steps;
  long kbase;
  if (y < 40) {
    A = x; ldA = 32000; W = Wx0; K = 32000; steps = 25;
    kbase = (long)y * 800;
  } else if (y < 42) {
    A = hs; ldA = 1024; W = Wh; K = 1024; steps = 16;
    kbase = (long)(y - 40) * 512;
  } else {
    A = hs + 65536; ldA = 1024; W = Wh + 4194304; K = 1024; steps = 16;
    kbase = (long)(y - 42) * 512;
  }
  const int tid = threadIdx.x;
  const int wv = tid >> 6;
  const int lane = tid & 63;
  const int l15 = lane & 15;
  const int l4 = lane >> 4;
  const int r3 = lane >> 3;  // 0..7: row-in-group for staging
  const int c = lane & 7;    // 16B chunk index for staging

  // staging sources: wave wv stages gate wv's 64 rows (8 rows per instr)
  const float* wsrc =
      W + (size_t)(wv * 1024 + blockIdx.x * 64 + r3) * K + kbase + c * 4;
  const float* asrc = A + (size_t)(wv * 16 + r3) * ldA + kbase + c * 4;
  // LDS write offsets (floats), swizzled
  const int wofs = (wv * 64 + r3) * 32 + ((c ^ r3) << 2);          // +i*256
  const int aofs = 8192 + (wv * 16 + r3) * 32 + ((c ^ r3) << 2);   // +j*256
  // fragment-read swizzled chunk offsets (floats)
  const int sw0 = ((2 * l4 + 0) ^ (l15 & 7)) << 2;
  const int sw1 = ((2 * l4 + 1) ^ (l15 & 7)) << 2;
  const int arow = 8192 + l15 * 32;     // + m*512
  const int wrow = (wv * 16 + l15) * 32; // + g*2048

  f32x4 acc[4][4];
#pragma unroll
  for (int g = 0; g < 4; ++g)
#pragma unroll
    for (int m = 0; m < 4; ++m)
      acc[g][m] = f32x4{0.f, 0.f, 0.f, 0.f};

  float4 wreg[8], areg[2];
  // prologue: load + write step 0
#pragma unroll
  for (int i = 0; i < 8; ++i)
    wreg[i] = *(const float4*)(wsrc + (size_t)i * 8 * K);
  areg[0] = *(const float4*)asrc;
  areg[1] = *(const float4*)(asrc + (size_t)8 * ldA);
#pragma unroll
  for (int i = 0; i < 8; ++i)
    *(float4*)&lds[wofs + i * 256] = wreg[i];
  *(float4*)&lds[aofs] = areg[0];
  *(float4*)&lds[aofs + 256] = areg[1];

  for (int s = 0; s < steps; ++s) {
    __syncthreads();
    if (s + 1 < steps) {  // issue next-step loads early (latency hides)
      const float* wp = wsrc + (size_t)(s + 1) * 32;
#pragma unroll
      for (int i = 0; i < 8; ++i)
        wreg[i] = *(const float4*)(wp + (size_t)i * 8 * K);
      const float* ap = asrc + (size_t)(s + 1) * 32;
      areg[0] = *(const float4*)ap;
      areg[1] = *(const float4*)(ap + (size_t)8 * ldA);
    }
    // compute step s from LDS
    short8 af[4];
#pragma unroll
    for (int m = 0; m < 4; ++m) {
      float4 a0 = *(const float4*)&lds[arow + m * 512 + sw0];
      float4 a1 = *(const float4*)&lds[arow + m * 512 + sw1];
      af[m] = cvt8(a0, a1);
    }
#pragma unroll
    for (int g = 0; g < 4; ++g) {
      float4 w0 = *(const float4*)&lds[wrow + g * 2048 + sw0];
      float4 w1 = *(const float4*)&lds[wrow + g * 2048 + sw1];
      short8 bfr = cvt8(w0, w1);
#pragma unroll
      for (int m = 0; m < 4; ++m)
        acc[g][m] = mfma16(af[m], bfr, acc[g][m]);
    }
    if (s + 1 < steps) {
      __syncthreads();  // everyone done reading LDS[s]
#pragma unroll
      for (int i = 0; i < 8; ++i)
        *(float4*)&lds[wofs + i * 256] = wreg[i];
      *(float4*)&lds[aofs] = areg[0];
      *(float4*)&lds[aofs + 256] = areg[1];
    }
  }

  // D mapping: row = l4*4 + r (+ m*16), col = l15
  const int h = blockIdx.x * 64 + wv * 16 + l15;
  float* zp = zpart + (size_t)y * 262144 + (size_t)(l4 * 4) * 4096 + h;
#pragma unroll
  for (int g = 0; g < 4; ++g)
#pragma unroll
    for (int m = 0; m < 4; ++m)
#pragma unroll
      for (int r = 0; r < 4; ++r)
        zp[(size_t)(m * 16 + r) * 4096 + g * 1024] = acc[g][m][r];
}

// ---------------------------------------------------------------------------
// Layer-1 x-path gates GEMM (bf16 A = out0), BK=64. 8 chunks of 128 k.
__global__ __launch_bounds__(256) void gates_b16(
    const ushort* __restrict__ A, const float* __restrict__ W,
    float* __restrict__ zbase) {
  const int chunk = blockIdx.y;
  const long kbase = (long)chunk * 128;
  const int tid = threadIdx.x;
  const int wv = tid >> 6;
  const int lane = tid & 63;
  const int l15 = lane & 15;
  const int l4 = lane >> 4;
  const int h = blockIdx.x * 64 + wv * 16 + l15;

  const ushort* arow[4];
#pragma unroll
  for (int m = 0; m < 4; ++m)
    arow[m] = A + (size_t)(m * 16 + l15) * 1024 + kbase + l4 * 8;
  const float* wrow[4];
#pragma unroll
  for (int g = 0; g < 4; ++g)
    wrow[g] = W + (size_t)(g * 1024 + h) * 1024 + kbase + l4 * 8;

  f32x4 acc[4][4];
#pragma unroll
  for (int g = 0; g < 4; ++g)
#pragma unroll
    for (int m = 0; m < 4; ++m)
      acc[g][m] = f32x4{0.f, 0.f, 0.f, 0.f};

#pragma unroll
  for (int s = 0; s < 2; ++s) {
    short8 af[4][2];
#pragma unroll
    for (int m = 0; m < 4; ++m) {
      const ushort* ap = arow[m] + (size_t)s * 64;
      af[m][0] = *(const short8*)ap;
      af[m][1] = *(const short8*)(ap + 32);
    }
#pragma unroll
    for (int g = 0; g < 4; ++g) {
      const float* wp = wrow[g] + (size_t)s * 64;
      float4 w00 = *(const float4*)wp;
      float4 w01 = *(const float4*)(wp + 4);
      float4 w10 = *(const float4*)(wp + 32);
      float4 w11 = *(const float4*)(wp + 36);
      short8 b0 = cvt8(w00, w01);
      short8 b1 = cvt8(w10, w11);
#pragma unroll
      for (int m = 0; m < 4; ++m) {
        acc[g][m] = mfma16(af[m][0], b0, acc[g][m]);
        acc[g][m] = mfma16(af[m][1], b1, acc[g][m]);
      }
    }
  }

  float* zp = zbase + (size_t)chunk * 262144 + (size_t)(l4 * 4) * 4096 + h;
#pragma unroll
  for (int g = 0; g < 4; ++g)
#pragma unroll
    for (int m = 0; m < 4; ++m)
#pragma unroll
      for (int r = 0; r < 4; ++r)
        zp[(size_t)(m * 16 + r) * 4096 + g * 1024] = acc[g][m][r];
}

// ---------------------------------------------------------------------------
// Reduce K-split partials + biases, apply LSTM cell, emit h (fp32 + bf16), c.
__global__ __launch_bounds__(256) void lstm_cell_k(
    const float* __restrict__ zpart, int nslots,
    const float* __restrict__ bx, const float* __restrict__ bhl,
    const float* __restrict__ c_in,
    float* __restrict__ h_out, float* __restrict__ c_out,
    ushort* __restrict__ h_out_b) {
  int idx = blockIdx.x * 256 + threadIdx.x;
  if (idx >= 64 * 1024) return;
  int h = idx & 1023;
  float z0 = bx[h] + bhl[h];
  float z1 = bx[1024 + h] + bhl[1024 + h];
  float z2 = bx[2048 + h] + bhl[2048 + h];
  float z3 = bx[3072 + h] + bhl[3072 + h];
  int b = idx >> 10;
  const float* zp = zpart + (size_t)b * 4096 + h;
  for (int s = 0; s < nslots; ++s) {
    const float* p = zp + (size_t)s * 262144;
    z0 += p[0];
    z1 += p[1024];
    z2 += p[2048];
    z3 += p[3072];
  }
  float f = 1.f / (1.f + expf(-z0));
  float i = 1.f / (1.f + expf(-z1));
  float o = 1.f / (1.f + expf(-z2));
  float g = tanhf(z3);
  float c = f * c_in[idx] + i * g;
  float hv = o * tanhf(c);
  h_out[idx] = hv;
  c_out[idx] = c;
  h_out_b[idx] = (ushort)f2bf(hv);
}

// ---------------------------------------------------------------------------
// Decoder GEMM, BK=64: one wave per block, 16 cols per wave -> 2000 blocks.
__global__ __launch_bounds__(64) void gemm_dec(
    const ushort* __restrict__ A, const float* __restrict__ W,
    const float* __restrict__ bias, float* __restrict__ logits) {
  const int lane = threadIdx.x;
  const int l15 = lane & 15;
  const int l4 = lane >> 4;
  const int col = blockIdx.x * 16 + l15;

  const ushort* arow[4];
#pragma unroll
  for (int m = 0; m < 4; ++m)
    arow[m] = A + (size_t)(m * 16 + l15) * 1024 + l4 * 8;
  const float* wrow = W + (size_t)col * 1024 + l4 * 8;

  f32x4 acc[4];
#pragma unroll
  for (int m = 0; m < 4; ++m) acc[m] = f32x4{0.f, 0.f, 0.f, 0.f};

#pragma unroll
  for (int s = 0; s < 16; ++s) {
    short8 af[4][2];
#pragma unroll
    for (int m = 0; m < 4; ++m) {
      const ushort* ap = arow[m] + (size_t)s * 64;
      af[m][0] = *(const short8*)ap;
      af[m][1] = *(const short8*)(ap + 32);
    }
    const float* wp = wrow + (size_t)s * 64;
    float4 w00 = *(const float4*)wp;
    float4 w01 = *(const float4*)(wp + 4);
    float4 w10 = *(const float4*)(wp + 32);
    float4 w11 = *(const float4*)(wp + 36);
    short8 b0 = cvt8(w00, w01);
    short8 b1 = cvt8(w10, w11);
#pragma unroll
    for (int m = 0; m < 4; ++m) {
      acc[m] = mfma16(af[m][0], b0, acc[m]);
      acc[m] = mfma16(af[m][1], b1, acc[m]);
    }
  }

  float bv = bias[col];
  float* lp = logits + (size_t)(l4 * 4) * 32000 + col;
#pragma unroll
  for (int m = 0; m < 4; ++m)
#pragma unroll
    for (int r = 0; r < 4; ++r)
      lp[(size_t)(m * 16 + r) * 32000] = acc[m][r] + bv;
}

// ---------------------------------------------------------------------------
// Log-softmax stage 1: per (row, quarter) partial max + expsum -> ms[row*4+c].
__global__ __launch_bounds__(256) void softmax_part1(
    const float* __restrict__ logits, float2* __restrict__ ms) {
  const int cx = blockIdx.x;   // 0..3
  const int b = blockIdx.y;    // 0..63
  const int tid = threadIdx.x;
  const int wv = tid >> 6;
  const int lane = tid & 63;
  const float* row = logits + (size_t)b * 32000 + cx * 8000;
  __shared__ float rbuf[4];

  float m = -1e30f;
  for (int i = tid; i < 8000; i += 256) m = fmaxf(m, row[i]);
#pragma unroll
  for (int d = 1; d < 64; d <<= 1) m = fmaxf(m, __shfl_xor(m, d));
  if (lane == 0) rbuf[wv] = m;
  __syncthreads();
  m = fmaxf(fmaxf(rbuf[0], rbuf[1]), fmaxf(rbuf[2], rbuf[3]));
  __syncthreads();

  float sum = 0.f;
  for (int i = tid; i < 8000; i += 256) sum += expf((row[i] - m) * 1.25f);
#pragma unroll
  for (int d = 1; d < 64; d <<= 1) sum += __shfl_xor(sum, d);
  if (lane == 0) rbuf[wv] = sum;
  __syncthreads();
  if (tid == 0) {
    sum = rbuf[0] + rbuf[1] + rbuf[2] + rbuf[3];
    ms[b * 4 + cx] = make_float2(m, sum);
  }
}

// Log-softmax stage 2: combine partials, write logp. 8 blocks per row.
__global__ __launch_bounds__(256) void softmax_part2(
    const float* __restrict__ logits, const float2* __restrict__ ms,
    float* __restrict__ logp) {
  const int cx = blockIdx.x;   // 0..7
  const int b = blockIdx.y;    // 0..63
  const int tid = threadIdx.x;

  float2 p0 = ms[b * 4 + 0], p1 = ms[b * 4 + 1];
  float2 p2 = ms[b * 4 + 2], p3 = ms[b * 4 + 3];
  float M = fmaxf(fmaxf(p0.x, p1.x), fmaxf(p2.x, p3.x));
  float S = p0.y * expf((p0.x - M) * 1.25f) + p1.y * expf((p1.x - M) * 1.25f) +
            p2.y * expf((p2.x - M) * 1.25f) + p3.y * expf((p3.x - M) * 1.25f);
  float lse = logf(S);

  const float* row = logits + (size_t)b * 32000 + cx * 4000;
  float* op = logp + (size_t)b * 32000 + cx * 4000;
  for (int i = tid; i < 4000; i += 256)
    op[i] = (row[i] - M) * 1.25f - lse;
}

// ---------------------------------------------------------------------------
extern "C" void kernel_launch(void* const* d_in, const int* in_sizes, int n_in,
                              void* d_out, int out_size, void* d_ws, size_t ws_size,
                              hipStream_t stream) {
  const float* x    = (const float*)d_in[0];
  const float* hs   = (const float*)d_in[1];
  const float* cs   = (const float*)d_in[2];
  const float* Wh   = (const float*)d_in[3];
  const float* bh   = (const float*)d_in[4];
  const float* Wx0  = (const float*)d_in[5];
  const float* bx0  = (const float*)d_in[6];
  const float* Wx1  = (const float*)d_in[7];
  const float* bx1  = (const float*)d_in[8];
  const float* Wdec = (const float*)d_in[9];
  const float* bdec = (const float*)d_in[10];

  float* out   = (float*)d_out;
  float* logp  = out;                 // 64*32000
  float* houts = out + 2048000;       // 2*64*1024
  float* couts = out + 2179072;       // 2*64*1024

  char* ws = (char*)d_ws;
  ushort* outb   = (ushort*)ws;                          //   262,144 B (2 layers)
  float*  logits = (float*)(ws + 262144);                // 8,192,000 B
  float2* ms     = (float2*)(ws + 262144 + 8192000);     //     2,048 B
  float*  zpart  = (float*)(ws + 262144 + 8192000 + 2048);
  // zpart slots (1 MiB each): [0,40) x0, [40,42) h0, [42,44) h1,
  // [44,52) layer-1 x-path.  Total 52 MiB.

  // 1) layer-0 gates + layer-1 h-path; 704 blocks <= 3/CU capacity
  gates_f32<<<dim3(16, 44), 256, 0, stream>>>(x, hs, Wx0, Wh, zpart);

  // 2) layer-0 cell: reduce slots [0, 42)
  lstm_cell_k<<<256, 256, 0, stream>>>(zpart, 42, bx0, bh, cs,
                                       houts, couts, outb);

  // 3) layer-1 x-path gates -> slots [44, 52)
  gates_b16<<<dim3(16, 8), 256, 0, stream>>>(
      outb, Wx1, zpart + (size_t)44 * 262144);

  // 4) layer-1 cell: reduce slots [42, 52)  (h1 partials + x-path)
  lstm_cell_k<<<256, 256, 0, stream>>>(zpart + (size_t)42 * 262144, 10,
                                       bx1, bh + 4096, cs + 65536,
                                       houts + 65536, couts + 65536,
                                       outb + 65536);

  // 5) decoder logits (2000 single-wave blocks), BK=64 streaming
  gemm_dec<<<2000, 64, 0, stream>>>(outb + 65536, Wdec, bdec, logits);

  // 6) log-softmax, two stages so all CUs participate
  softmax_part1<<<dim3(4, 64), 256, 0, stream>>>(logits, ms);
  softmax_part2<<<dim3(8, 64), 256, 0, stream>>>(logits, ms, logp);
}

// Round 10
// 280.602 us; speedup vs baseline: 1.9072x; 1.9072x over previous
//
#include <hip/hip_runtime.h>
#include <hip/hip_bf16.h>
#include <cstdint>

#define DI __device__ __forceinline__

typedef __attribute__((ext_vector_type(8))) short short8;
typedef __attribute__((ext_vector_type(4))) float f32x4;
typedef __attribute__((ext_vector_type(4))) int int4v;

DI f32x4 mfma16(short8 a, short8 b, f32x4 c) {
  return __builtin_amdgcn_mfma_f32_16x16x32_bf16(a, b, c, 0, 0, 0);
}

// fp32 -> bf16 round-to-nearest-even (bit trick, matches v_cvt rounding)
DI uint32_t f2bf(float f) {
  uint32_t u = __float_as_uint(f);
  return (u + 0x7fffu + ((u >> 16) & 1u)) >> 16;
}

DI uint32_t pk2(float a, float b) {
  return f2bf(a) | (f2bf(b) << 16);
}

DI short8 cvt8(float4 a, float4 b) {
  int4v t;
  t.x = (int)pk2(a.x, a.y);
  t.y = (int)pk2(a.z, a.w);
  t.z = (int)pk2(b.x, b.y);
  t.w = (int)pk2(b.z, b.w);
  return __builtin_bit_cast(short8, t);
}

// ---------------------------------------------------------------------------
// Convert x (64x32000) and hidden_states (2x64x1024) fp32 -> bf16 once.
__global__ __launch_bounds__(256) void convert_k(
    const float* __restrict__ x, const float* __restrict__ hs,
    ushort* __restrict__ xb, ushort* __restrict__ hb) {
  const int NX4 = 512000;   // 2048000/4
  const int NH4 = 32768;    // 131072/4
  int i = blockIdx.x * 256 + threadIdx.x;
  if (i < NX4) {
    float4 v = *(const float4*)(x + 4 * (size_t)i);
    uint2 o;
    o.x = pk2(v.x, v.y);
    o.y = pk2(v.z, v.w);
    *(uint2*)(xb + 4 * (size_t)i) = o;
  } else if (i < NX4 + NH4) {
    int j = i - NX4;
    float4 v = *(const float4*)(hs + 4 * (size_t)j);
    uint2 o;
    o.x = pk2(v.x, v.y);
    o.y = pk2(v.z, v.w);
    *(uint2*)(hb + 4 * (size_t)j) = o;
  }
}

// ---------------------------------------------------------------------------
// Gates GEMM, BK=64, register W-prefetch pipeline (no LDS, no barriers).
// Per iteration: A loads for step s issued FIRST (oldest -> vmcnt releases
// MFMAs on A only), then 16 W loads for step s+1, then 32 MFMAs consuming
// the PREVIOUS iteration's converted wb regs, then cvt wt->wb. W's ~900cy
// HBM latency is covered by a full compute phase; each W row is consumed
// as one 256 B granule per step (no overfetch).
// Chunk slots (blockIdx.y):
//   y in [0,25)  : xb @ Wx0^T     (K=32000, 25 chunks x 20 steps of 64)
//   y in [25,27) : h0 @ Wh[0]^T   (K=1024, 2 chunks x 8 steps)
//   y in [27,29) : h1 @ Wh[1]^T   (K=1024, 2 chunks x 8 steps)
__global__ __launch_bounds__(256, 2) void gates_pf(
    const ushort* __restrict__ xb, const ushort* __restrict__ hb,
    const float* __restrict__ Wx0, const float* __restrict__ Wh,
    float* __restrict__ zpart) {
  const int y = blockIdx.y;
  const ushort* A;
  const float* W;
  int ldA, K, steps;
  long kbase;
  if (y < 25) {
    A = xb; ldA = 32000; W = Wx0; K = 32000; steps = 20;
    kbase = (long)y * 1280;
  } else if (y < 27) {
    A = hb; ldA = 1024; W = Wh; K = 1024; steps = 8;
    kbase = (long)(y - 25) * 512;
  } else {
    A = hb + 65536; ldA = 1024; W = Wh + 4194304; K = 1024; steps = 8;
    kbase = (long)(y - 27) * 512;
  }
  const int tid = threadIdx.x;
  const int wv = tid >> 6;
  const int lane = tid & 63;
  const int l15 = lane & 15;
  const int l4 = lane >> 4;
  const int h = blockIdx.x * 64 + wv * 16 + l15;

  const ushort* arow[4];
#pragma unroll
  for (int m = 0; m < 4; ++m)
    arow[m] = A + (size_t)(m * 16 + l15) * ldA + kbase + l4 * 8;
  const float* wrow[4];
#pragma unroll
  for (int g = 0; g < 4; ++g)
    wrow[g] = W + (size_t)(g * 1024 + h) * K + kbase + l4 * 8;

  f32x4 acc[4][4];
#pragma unroll
  for (int g = 0; g < 4; ++g)
#pragma unroll
    for (int m = 0; m < 4; ++m)
      acc[g][m] = f32x4{0.f, 0.f, 0.f, 0.f};

  float4 wt[4][4];   // in-flight W (next step), fp32
  short8 wb0[4], wb1[4];  // current step W, bf16

  // prologue: load + convert step 0's W
#pragma unroll
  for (int g = 0; g < 4; ++g) {
    const float* wp = wrow[g];
    wt[g][0] = *(const float4*)wp;
    wt[g][1] = *(const float4*)(wp + 4);
    wt[g][2] = *(const float4*)(wp + 32);
    wt[g][3] = *(const float4*)(wp + 36);
  }
#pragma unroll
  for (int g = 0; g < 4; ++g) {
    wb0[g] = cvt8(wt[g][0], wt[g][1]);
    wb1[g] = cvt8(wt[g][2], wt[g][3]);
  }

  for (int s = 0; s < steps; ++s) {
    // 1) A loads for step s (oldest outstanding -> MFMAs wait only on these)
    short8 af0[4], af1[4];
#pragma unroll
    for (int m = 0; m < 4; ++m) {
      const ushort* ap = arow[m] + (size_t)s * 64;
      af0[m] = *(const short8*)ap;
      af1[m] = *(const short8*)(ap + 32);
    }
    // 2) issue W loads for step s+1 (land during/after the MFMA phase)
    if (s + 1 < steps) {
#pragma unroll
      for (int g = 0; g < 4; ++g) {
        const float* wp = wrow[g] + (size_t)(s + 1) * 64;
        wt[g][0] = *(const float4*)wp;
        wt[g][1] = *(const float4*)(wp + 4);
        wt[g][2] = *(const float4*)(wp + 32);
        wt[g][3] = *(const float4*)(wp + 36);
      }
    }
    // 3) compute step s from wb (in regs since last iteration)
#pragma unroll
    for (int g = 0; g < 4; ++g)
#pragma unroll
      for (int m = 0; m < 4; ++m) {
        acc[g][m] = mfma16(af0[m], wb0[g], acc[g][m]);
        acc[g][m] = mfma16(af1[m], wb1[g], acc[g][m]);
      }
    // 4) convert the landed W for the next step
    if (s + 1 < steps) {
#pragma unroll
      for (int g = 0; g < 4; ++g) {
        wb0[g] = cvt8(wt[g][0], wt[g][1]);
        wb1[g] = cvt8(wt[g][2], wt[g][3]);
      }
    }
  }

  // D mapping: row = l4*4 + r (+ m*16), col = l15
  float* zp = zpart + (size_t)y * 262144 + (size_t)(l4 * 4) * 4096 + h;
#pragma unroll
  for (int g = 0; g < 4; ++g)
#pragma unroll
    for (int m = 0; m < 4; ++m)
#pragma unroll
      for (int r = 0; r < 4; ++r)
        zp[(size_t)(m * 16 + r) * 4096 + g * 1024] = acc[g][m][r];
}

// ---------------------------------------------------------------------------
// Layer-1 x-path gates GEMM (bf16 A = out0). 16 chunks of 64 k (R4-proven).
__global__ __launch_bounds__(256) void gates_b16(
    const ushort* __restrict__ A, const float* __restrict__ W,
    float* __restrict__ zbase) {
  const int chunk = blockIdx.y;
  const long kbase = (long)chunk * 64;
  const int tid = threadIdx.x;
  const int wv = tid >> 6;
  const int lane = tid & 63;
  const int l15 = lane & 15;
  const int l4 = lane >> 4;
  const int h = blockIdx.x * 64 + wv * 16 + l15;

  const ushort* arow[4];
#pragma unroll
  for (int m = 0; m < 4; ++m)
    arow[m] = A + (size_t)(m * 16 + l15) * 1024 + kbase + l4 * 8;
  const float* wrow[4];
#pragma unroll
  for (int g = 0; g < 4; ++g)
    wrow[g] = W + (size_t)(g * 1024 + h) * 1024 + kbase + l4 * 8;

  f32x4 acc[4][4];
#pragma unroll
  for (int g = 0; g < 4; ++g)
#pragma unroll
    for (int m = 0; m < 4; ++m)
      acc[g][m] = f32x4{0.f, 0.f, 0.f, 0.f};

#pragma unroll
  for (int s = 0; s < 2; ++s) {
    short8 af[4];
#pragma unroll
    for (int m = 0; m < 4; ++m)
      af[m] = *(const short8*)(arow[m] + (size_t)s * 32);
#pragma unroll
    for (int g = 0; g < 4; ++g) {
      const float* wp = wrow[g] + (size_t)s * 32;
      float4 w0 = *(const float4*)wp;
      float4 w1 = *(const float4*)(wp + 4);
      short8 bfr = cvt8(w0, w1);
#pragma unroll
      for (int m = 0; m < 4; ++m)
        acc[g][m] = mfma16(af[m], bfr, acc[g][m]);
    }
  }

  float* zp = zbase + (size_t)chunk * 262144 + (size_t)(l4 * 4) * 4096 + h;
#pragma unroll
  for (int g = 0; g < 4; ++g)
#pragma unroll
    for (int m = 0; m < 4; ++m)
#pragma unroll
      for (int r = 0; r < 4; ++r)
        zp[(size_t)(m * 16 + r) * 4096 + g * 1024] = acc[g][m][r];
}

// ---------------------------------------------------------------------------
// Reduce K-split partials + biases, apply LSTM cell, emit h (fp32 + bf16), c.
__global__ __launch_bounds__(256) void lstm_cell_k(
    const float* __restrict__ zpart, int nslots,
    const float* __restrict__ bx, const float* __restrict__ bhl,
    const float* __restrict__ c_in,
    float* __restrict__ h_out, float* __restrict__ c_out,
    ushort* __restrict__ h_out_b) {
  int idx = blockIdx.x * 256 + threadIdx.x;
  if (idx >= 64 * 1024) return;
  int h = idx & 1023;
  float z0 = bx[h] + bhl[h];
  float z1 = bx[1024 + h] + bhl[1024 + h];
  float z2 = bx[2048 + h] + bhl[2048 + h];
  float z3 = bx[3072 + h] + bhl[3072 + h];
  int b = idx >> 10;
  const float* zp = zpart + (size_t)b * 4096 + h;
  for (int s = 0; s < nslots; ++s) {
    const float* p = zp + (size_t)s * 262144;
    z0 += p[0];
    z1 += p[1024];
    z2 += p[2048];
    z3 += p[3072];
  }
  float f = 1.f / (1.f + expf(-z0));
  float i = 1.f / (1.f + expf(-z1));
  float o = 1.f / (1.f + expf(-z2));
  float g = tanhf(z3);
  float c = f * c_in[idx] + i * g;
  float hv = o * tanhf(c);
  h_out[idx] = hv;
  c_out[idx] = c;
  h_out_b[idx] = (ushort)f2bf(hv);
}

// ---------------------------------------------------------------------------
// Decoder GEMM (R4-proven): one wave per block, 16 cols per wave, BK=32.
__global__ __launch_bounds__(64) void gemm_dec(
    const ushort* __restrict__ A, const float* __restrict__ W,
    const float* __restrict__ bias, float* __restrict__ logits) {
  const int lane = threadIdx.x;
  const int l15 = lane & 15;
  const int l4 = lane >> 4;
  const int col = blockIdx.x * 16 + l15;

  const ushort* arow[4];
#pragma unroll
  for (int m = 0; m < 4; ++m)
    arow[m] = A + (size_t)(m * 16 + l15) * 1024 + l4 * 8;
  const float* wrow = W + (size_t)col * 1024 + l4 * 8;

  f32x4 acc[4];
#pragma unroll
  for (int m = 0; m < 4; ++m) acc[m] = f32x4{0.f, 0.f, 0.f, 0.f};

  for (int s = 0; s < 32; ++s) {
    short8 af[4];
#pragma unroll
    for (int m = 0; m < 4; ++m)
      af[m] = *(const short8*)(arow[m] + (size_t)s * 32);
    const float* wp = wrow + (size_t)s * 32;
    float4 w0 = *(const float4*)wp;
    float4 w1 = *(const float4*)(wp + 4);
    short8 bfr = cvt8(w0, w1);
#pragma unroll
    for (int m = 0; m < 4; ++m)
      acc[m] = mfma16(af[m], bfr, acc[m]);
  }

  float bv = bias[col];
  float* lp = logits + (size_t)(l4 * 4) * 32000 + col;
#pragma unroll
  for (int m = 0; m < 4; ++m)
#pragma unroll
    for (int r = 0; r < 4; ++r)
      lp[(size_t)(m * 16 + r) * 32000] = acc[m][r] + bv;
}

// ---------------------------------------------------------------------------
// Log-softmax stage 1: per (row, quarter) partial max + expsum -> ms[row*4+c].
__global__ __launch_bounds__(256) void softmax_part1(
    const float* __restrict__ logits, float2* __restrict__ ms) {
  const int cx = blockIdx.x;   // 0..3
  const int b = blockIdx.y;    // 0..63
  const int tid = threadIdx.x;
  const int wv = tid >> 6;
  const int lane = tid & 63;
  const float* row = logits + (size_t)b * 32000 + cx * 8000;
  __shared__ float rbuf[4];

  float m = -1e30f;
  for (int i = tid; i < 8000; i += 256) m = fmaxf(m, row[i]);
#pragma unroll
  for (int d = 1; d < 64; d <<= 1) m = fmaxf(m, __shfl_xor(m, d));
  if (lane == 0) rbuf[wv] = m;
  __syncthreads();
  m = fmaxf(fmaxf(rbuf[0], rbuf[1]), fmaxf(rbuf[2], rbuf[3]));
  __syncthreads();

  float sum = 0.f;
  for (int i = tid; i < 8000; i += 256) sum += expf((row[i] - m) * 1.25f);
#pragma unroll
  for (int d = 1; d < 64; d <<= 1) sum += __shfl_xor(sum, d);
  if (lane == 0) rbuf[wv] = sum;
  __syncthreads();
  if (tid == 0) {
    sum = rbuf[0] + rbuf[1] + rbuf[2] + rbuf[3];
    ms[b * 4 + cx] = make_float2(m, sum);
  }
}

// Log-softmax stage 2: combine partials, write logp. 8 blocks per row.
__global__ __launch_bounds__(256) void softmax_part2(
    const float* __restrict__ logits, const float2* __restrict__ ms,
    float* __restrict__ logp) {
  const int cx = blockIdx.x;   // 0..7
  const int b = blockIdx.y;    // 0..63
  const int tid = threadIdx.x;

  float2 p0 = ms[b * 4 + 0], p1 = ms[b * 4 + 1];
  float2 p2 = ms[b * 4 + 2], p3 = ms[b * 4 + 3];
  float M = fmaxf(fmaxf(p0.x, p1.x), fmaxf(p2.x, p3.x));
  float S = p0.y * expf((p0.x - M) * 1.25f) + p1.y * expf((p1.x - M) * 1.25f) +
            p2.y * expf((p2.x - M) * 1.25f) + p3.y * expf((p3.x - M) * 1.25f);
  float lse = logf(S);

  const float* row = logits + (size_t)b * 32000 + cx * 4000;
  float* op = logp + (size_t)b * 32000 + cx * 4000;
  for (int i = tid; i < 4000; i += 256)
    op[i] = (row[i] - M) * 1.25f - lse;
}

// ---------------------------------------------------------------------------
extern "C" void kernel_launch(void* const* d_in, const int* in_sizes, int n_in,
                              void* d_out, int out_size, void* d_ws, size_t ws_size,
                              hipStream_t stream) {
  const float* x    = (const float*)d_in[0];
  const float* hs   = (const float*)d_in[1];
  const float* cs   = (const float*)d_in[2];
  const float* Wh   = (const float*)d_in[3];
  const float* bh   = (const float*)d_in[4];
  const float* Wx0  = (const float*)d_in[5];
  const float* bx0  = (const float*)d_in[6];
  const float* Wx1  = (const float*)d_in[7];
  const float* bx1  = (const float*)d_in[8];
  const float* Wdec = (const float*)d_in[9];
  const float* bdec = (const float*)d_in[10];

  float* out   = (float*)d_out;
  float* logp  = out;                 // 64*32000
  float* houts = out + 2048000;       // 2*64*1024
  float* couts = out + 2179072;       // 2*64*1024

  char* ws = (char*)d_ws;
  ushort* xb     = (ushort*)ws;                              // 4,096,000 B
  ushort* hb     = (ushort*)(ws + 4096000);                  //   262,144 B
  ushort* outb   = (ushort*)(ws + 4358144);                  //   262,144 B
  float*  logits = (float*)(ws + 4620288);                   // 8,192,000 B
  float2* ms     = (float2*)(ws + 12812288);                 //     2,048 B
  float*  zpart  = (float*)(ws + 12814336);
  // zpart slots (1 MiB each): [0,25) x0, [25,27) h0, [27,29) h1,
  // [29,45) layer-1 x-path.  Total 45 MiB; ws total ~57 MiB.

  // 1) fp32 -> bf16 activations (x and both hidden states)
  convert_k<<<2128, 256, 0, stream>>>(x, hs, xb, hb);

  // 2) layer-0 gates + layer-1 h-path, W-prefetch BK=64 pipeline
  gates_pf<<<dim3(16, 29), 256, 0, stream>>>(xb, hb, Wx0, Wh, zpart);

  // 3) layer-0 cell: reduce slots [0, 27)
  lstm_cell_k<<<256, 256, 0, stream>>>(zpart, 27, bx0, bh, cs,
                                       houts, couts, outb);

  // 4) layer-1 x-path gates -> slots [29, 45)
  gates_b16<<<dim3(16, 16), 256, 0, stream>>>(
      outb, Wx1, zpart + (size_t)29 * 262144);

  // 5) layer-1 cell: reduce slots [27, 45)  (h1 partials + x-path)
  lstm_cell_k<<<256, 256, 0, stream>>>(zpart + (size_t)27 * 262144, 18,
                                       bx1, bh + 4096, cs + 65536,
                                       houts + 65536, couts + 65536,
                                       outb + 65536);

  // 6) decoder logits (2000 single-wave blocks)
  gemm_dec<<<2000, 64, 0, stream>>>(outb + 65536, Wdec, bdec, logits);

  // 7) log-softmax, two stages so all CUs participate
  softmax_part1<<<dim3(4, 64), 256, 0, stream>>>(logits, ms);
  softmax_part2<<<dim3(8, 64), 256, 0, stream>>>(logits, ms, logp);
}

// Round 11
// 277.086 us; speedup vs baseline: 1.9314x; 1.0127x over previous
//
#include <hip/hip_runtime.h>
#include <hip/hip_bf16.h>
#include <cstdint>

#define DI __device__ __forceinline__

typedef __attribute__((ext_vector_type(8))) short short8;
typedef __attribute__((ext_vector_type(4))) float f32x4;
typedef __attribute__((ext_vector_type(4))) int int4v;

DI f32x4 mfma16(short8 a, short8 b, f32x4 c) {
  return __builtin_amdgcn_mfma_f32_16x16x32_bf16(a, b, c, 0, 0, 0);
}

// fp32 -> bf16 round-to-nearest-even (bit trick, matches v_cvt rounding)
DI uint32_t f2bf(float f) {
  uint32_t u = __float_as_uint(f);
  return (u + 0x7fffu + ((u >> 16) & 1u)) >> 16;
}

DI uint32_t pk2(float a, float b) {
  return f2bf(a) | (f2bf(b) << 16);
}

DI short8 cvt8(float4 a, float4 b) {
  int4v t;
  t.x = (int)pk2(a.x, a.y);
  t.y = (int)pk2(a.z, a.w);
  t.z = (int)pk2(b.x, b.y);
  t.w = (int)pk2(b.z, b.w);
  return __builtin_bit_cast(short8, t);
}

// ---------------------------------------------------------------------------
// Convert x (64x32000) and hidden_states (2x64x1024) fp32 -> bf16 once.
__global__ __launch_bounds__(256) void convert_k(
    const float* __restrict__ x, const float* __restrict__ hs,
    ushort* __restrict__ xb, ushort* __restrict__ hb) {
  const int NX4 = 512000;   // 2048000/4
  const int NH4 = 32768;    // 131072/4
  int i = blockIdx.x * 256 + threadIdx.x;
  if (i < NX4) {
    float4 v = *(const float4*)(x + 4 * (size_t)i);
    uint2 o;
    o.x = pk2(v.x, v.y);
    o.y = pk2(v.z, v.w);
    *(uint2*)(xb + 4 * (size_t)i) = o;
  } else if (i < NX4 + NH4) {
    int j = i - NX4;
    float4 v = *(const float4*)(hs + 4 * (size_t)j);
    uint2 o;
    o.x = pk2(v.x, v.y);
    o.y = pk2(v.z, v.w);
    *(uint2*)(hb + 4 * (size_t)j) = o;
  }
}

// ---------------------------------------------------------------------------
// Gates GEMM, BK=64, depth-2 register W-prefetch, 2 gates per block.
// blockIdx.z selects the gate pair {2z, 2z+1}. Per wave: 16 cols x 2 gates.
// Register budget (~160 VGPR incl. acc): acc 32 + wtA/wtB 64 + wb 16 + af 32
// -> 2 waves/SIMD sustained, no spill. W(s) consumed TWO compute phases
// after issue (~700-900cy) -> HBM latency covered. Loop unrolled x2 with
// named wtA/wtB (no runtime-indexed register arrays).
// Chunk slots (blockIdx.y):
//   y in [0,25)  : xb @ Wx0^T     (K=32000, 25 chunks x 20 steps of 64)
//   y in [25,27) : h0 @ Wh[0]^T   (K=1024, 2 chunks x 8 steps)
//   y in [27,29) : h1 @ Wh[1]^T   (K=1024, 2 chunks x 8 steps)
__global__ __launch_bounds__(256, 2) void gates_pf2(
    const ushort* __restrict__ xb, const ushort* __restrict__ hb,
    const float* __restrict__ Wx0, const float* __restrict__ Wh,
    float* __restrict__ zpart) {
  const int y = blockIdx.y;
  const int gz = blockIdx.z;  // gate pair: gates 2gz, 2gz+1
  const ushort* A;
  const float* W;
  int ldA, K, steps;
  long kbase;
  if (y < 25) {
    A = xb; ldA = 32000; W = Wx0; K = 32000; steps = 20;
    kbase = (long)y * 1280;
  } else if (y < 27) {
    A = hb; ldA = 1024; W = Wh; K = 1024; steps = 8;
    kbase = (long)(y - 25) * 512;
  } else {
    A = hb + 65536; ldA = 1024; W = Wh + 4194304; K = 1024; steps = 8;
    kbase = (long)(y - 27) * 512;
  }
  const int tid = threadIdx.x;
  const int wv = tid >> 6;
  const int lane = tid & 63;
  const int l15 = lane & 15;
  const int l4 = lane >> 4;
  const int h = blockIdx.x * 64 + wv * 16 + l15;

  const ushort* arow[4];
#pragma unroll
  for (int m = 0; m < 4; ++m)
    arow[m] = A + (size_t)(m * 16 + l15) * ldA + kbase + l4 * 8;
  const float* wrow[2];
#pragma unroll
  for (int gi = 0; gi < 2; ++gi)
    wrow[gi] = W + (size_t)((gz * 2 + gi) * 1024 + h) * K + kbase + l4 * 8;

  f32x4 acc[2][4];
#pragma unroll
  for (int gi = 0; gi < 2; ++gi)
#pragma unroll
    for (int m = 0; m < 4; ++m)
      acc[gi][m] = f32x4{0.f, 0.f, 0.f, 0.f};

  // depth-2 in-flight W: wtA = W(s even slots), wtB = W(s odd slots)
  float4 wtA[2][4], wtB[2][4];

#define LOADW(dst, ss)                                             \
  {                                                                \
    _Pragma("unroll") for (int gi = 0; gi < 2; ++gi) {             \
      const float* wp = wrow[gi] + (size_t)(ss) * 64;              \
      dst[gi][0] = *(const float4*)wp;                             \
      dst[gi][1] = *(const float4*)(wp + 4);                       \
      dst[gi][2] = *(const float4*)(wp + 32);                      \
      dst[gi][3] = *(const float4*)(wp + 36);                      \
    }                                                              \
  }

#define SUBITER(wt, ss, reload_s)                                  \
  {                                                                \
    short8 af0[4], af1[4];                                         \
    _Pragma("unroll") for (int m = 0; m < 4; ++m) {                \
      const ushort* ap = arow[m] + (size_t)(ss) * 64;              \
      af0[m] = *(const short8*)ap;                                 \
      af1[m] = *(const short8*)(ap + 32);                          \
    }                                                              \
    short8 wb0[2], wb1[2];                                         \
    _Pragma("unroll") for (int gi = 0; gi < 2; ++gi) {             \
      wb0[gi] = cvt8(wt[gi][0], wt[gi][1]);                        \
      wb1[gi] = cvt8(wt[gi][2], wt[gi][3]);                        \
    }                                                              \
    if ((reload_s) < steps) LOADW(wt, (reload_s));                 \
    _Pragma("unroll") for (int gi = 0; gi < 2; ++gi)               \
        _Pragma("unroll") for (int m = 0; m < 4; ++m) {            \
      acc[gi][m] = mfma16(af0[m], wb0[gi], acc[gi][m]);            \
      acc[gi][m] = mfma16(af1[m], wb1[gi], acc[gi][m]);            \
    }                                                              \
  }

  // prologue: W(0) -> wtA, W(1) -> wtB
  LOADW(wtA, 0);
  LOADW(wtB, 1);

  for (int s = 0; s < steps; s += 2) {
    SUBITER(wtA, s, s + 2);      // consume W(s), reload wtA with W(s+2)
    SUBITER(wtB, s + 1, s + 3);  // consume W(s+1), reload wtB with W(s+3)
  }
#undef SUBITER
#undef LOADW

  // D mapping: row = l4*4 + r (+ m*16), col = l15
  float* zp = zpart + (size_t)y * 262144 + (size_t)(l4 * 4) * 4096 +
              (gz * 2) * 1024 + h;
#pragma unroll
  for (int gi = 0; gi < 2; ++gi)
#pragma unroll
    for (int m = 0; m < 4; ++m)
#pragma unroll
      for (int r = 0; r < 4; ++r)
        zp[(size_t)(m * 16 + r) * 4096 + gi * 1024] = acc[gi][m][r];
}

// ---------------------------------------------------------------------------
// Layer-1 x-path gates GEMM (bf16 A = out0). 16 chunks of 64 k (R4-proven).
__global__ __launch_bounds__(256) void gates_b16(
    const ushort* __restrict__ A, const float* __restrict__ W,
    float* __restrict__ zbase) {
  const int chunk = blockIdx.y;
  const long kbase = (long)chunk * 64;
  const int tid = threadIdx.x;
  const int wv = tid >> 6;
  const int lane = tid & 63;
  const int l15 = lane & 15;
  const int l4 = lane >> 4;
  const int h = blockIdx.x * 64 + wv * 16 + l15;

  const ushort* arow[4];
#pragma unroll
  for (int m = 0; m < 4; ++m)
    arow[m] = A + (size_t)(m * 16 + l15) * 1024 + kbase + l4 * 8;
  const float* wrow[4];
#pragma unroll
  for (int g = 0; g < 4; ++g)
    wrow[g] = W + (size_t)(g * 1024 + h) * 1024 + kbase + l4 * 8;

  f32x4 acc[4][4];
#pragma unroll
  for (int g = 0; g < 4; ++g)
#pragma unroll
    for (int m = 0; m < 4; ++m)
      acc[g][m] = f32x4{0.f, 0.f, 0.f, 0.f};

#pragma unroll
  for (int s = 0; s < 2; ++s) {
    short8 af[4];
#pragma unroll
    for (int m = 0; m < 4; ++m)
      af[m] = *(const short8*)(arow[m] + (size_t)s * 32);
#pragma unroll
    for (int g = 0; g < 4; ++g) {
      const float* wp = wrow[g] + (size_t)s * 32;
      float4 w0 = *(const float4*)wp;
      float4 w1 = *(const float4*)(wp + 4);
      short8 bfr = cvt8(w0, w1);
#pragma unroll
      for (int m = 0; m < 4; ++m)
        acc[g][m] = mfma16(af[m], bfr, acc[g][m]);
    }
  }

  float* zp = zbase + (size_t)chunk * 262144 + (size_t)(l4 * 4) * 4096 + h;
#pragma unroll
  for (int g = 0; g < 4; ++g)
#pragma unroll
    for (int m = 0; m < 4; ++m)
#pragma unroll
      for (int r = 0; r < 4; ++r)
        zp[(size_t)(m * 16 + r) * 4096 + g * 1024] = acc[g][m][r];
}

// ---------------------------------------------------------------------------
// Reduce K-split partials + biases, apply LSTM cell, emit h (fp32 + bf16), c.
__global__ __launch_bounds__(256) void lstm_cell_k(
    const float* __restrict__ zpart, int nslots,
    const float* __restrict__ bx, const float* __restrict__ bhl,
    const float* __restrict__ c_in,
    float* __restrict__ h_out, float* __restrict__ c_out,
    ushort* __restrict__ h_out_b) {
  int idx = blockIdx.x * 256 + threadIdx.x;
  if (idx >= 64 * 1024) return;
  int h = idx & 1023;
  float z0 = bx[h] + bhl[h];
  float z1 = bx[1024 + h] + bhl[1024 + h];
  float z2 = bx[2048 + h] + bhl[2048 + h];
  float z3 = bx[3072 + h] + bhl[3072 + h];
  int b = idx >> 10;
  const float* zp = zpart + (size_t)b * 4096 + h;
  for (int s = 0; s < nslots; ++s) {
    const float* p = zp + (size_t)s * 262144;
    z0 += p[0];
    z1 += p[1024];
    z2 += p[2048];
    z3 += p[3072];
  }
  float f = 1.f / (1.f + expf(-z0));
  float i = 1.f / (1.f + expf(-z1));
  float o = 1.f / (1.f + expf(-z2));
  float g = tanhf(z3);
  float c = f * c_in[idx] + i * g;
  float hv = o * tanhf(c);
  h_out[idx] = hv;
  c_out[idx] = c;
  h_out_b[idx] = (ushort)f2bf(hv);
}

// ---------------------------------------------------------------------------
// Decoder GEMM (R4-proven): one wave per block, 16 cols per wave, BK=32.
__global__ __launch_bounds__(64) void gemm_dec(
    const ushort* __restrict__ A, const float* __restrict__ W,
    const float* __restrict__ bias, float* __restrict__ logits) {
  const int lane = threadIdx.x;
  const int l15 = lane & 15;
  const int l4 = lane >> 4;
  const int col = blockIdx.x * 16 + l15;

  const ushort* arow[4];
#pragma unroll
  for (int m = 0; m < 4; ++m)
    arow[m] = A + (size_t)(m * 16 + l15) * 1024 + l4 * 8;
  const float* wrow = W + (size_t)col * 1024 + l4 * 8;

  f32x4 acc[4];
#pragma unroll
  for (int m = 0; m < 4; ++m) acc[m] = f32x4{0.f, 0.f, 0.f, 0.f};

  for (int s = 0; s < 32; ++s) {
    short8 af[4];
#pragma unroll
    for (int m = 0; m < 4; ++m)
      af[m] = *(const short8*)(arow[m] + (size_t)s * 32);
    const float* wp = wrow + (size_t)s * 32;
    float4 w0 = *(const float4*)wp;
    float4 w1 = *(const float4*)(wp + 4);
    short8 bfr = cvt8(w0, w1);
#pragma unroll
    for (int m = 0; m < 4; ++m)
      acc[m] = mfma16(af[m], bfr, acc[m]);
  }

  float bv = bias[col];
  float* lp = logits + (size_t)(l4 * 4) * 32000 + col;
#pragma unroll
  for (int m = 0; m < 4; ++m)
#pragma unroll
    for (int r = 0; r < 4; ++r)
      lp[(size_t)(m * 16 + r) * 32000] = acc[m][r] + bv;
}

// ---------------------------------------------------------------------------
// Log-softmax stage 1: per (row, quarter) partial max + expsum -> ms[row*4+c].
__global__ __launch_bounds__(256) void softmax_part1(
    const float* __restrict__ logits, float2* __restrict__ ms) {
  const int cx = blockIdx.x;   // 0..3
  const int b = blockIdx.y;    // 0..63
  const int tid = threadIdx.x;
  const int wv = tid >> 6;
  const int lane = tid & 63;
  const float* row = logits + (size_t)b * 32000 + cx * 8000;
  __shared__ float rbuf[4];

  float m = -1e30f;
  for (int i = tid; i < 8000; i += 256) m = fmaxf(m, row[i]);
#pragma unroll
  for (int d = 1; d < 64; d <<= 1) m = fmaxf(m, __shfl_xor(m, d));
  if (lane == 0) rbuf[wv] = m;
  __syncthreads();
  m = fmaxf(fmaxf(rbuf[0], rbuf[1]), fmaxf(rbuf[2], rbuf[3]));
  __syncthreads();

  float sum = 0.f;
  for (int i = tid; i < 8000; i += 256) sum += expf((row[i] - m) * 1.25f);
#pragma unroll
  for (int d = 1; d < 64; d <<= 1) sum += __shfl_xor(sum, d);
  if (lane == 0) rbuf[wv] = sum;
  __syncthreads();
  if (tid == 0) {
    sum = rbuf[0] + rbuf[1] + rbuf[2] + rbuf[3];
    ms[b * 4 + cx] = make_float2(m, sum);
  }
}

// Log-softmax stage 2: combine partials, write logp. 8 blocks per row.
__global__ __launch_bounds__(256) void softmax_part2(
    const float* __restrict__ logits, const float2* __restrict__ ms,
    float* __restrict__ logp) {
  const int cx = blockIdx.x;   // 0..7
  const int b = blockIdx.y;    // 0..63
  const int tid = threadIdx.x;

  float2 p0 = ms[b * 4 + 0], p1 = ms[b * 4 + 1];
  float2 p2 = ms[b * 4 + 2], p3 = ms[b * 4 + 3];
  float M = fmaxf(fmaxf(p0.x, p1.x), fmaxf(p2.x, p3.x));
  float S = p0.y * expf((p0.x - M) * 1.25f) + p1.y * expf((p1.x - M) * 1.25f) +
            p2.y * expf((p2.x - M) * 1.25f) + p3.y * expf((p3.x - M) * 1.25f);
  float lse = logf(S);

  const float* row = logits + (size_t)b * 32000 + cx * 4000;
  float* op = logp + (size_t)b * 32000 + cx * 4000;
  for (int i = tid; i < 4000; i += 256)
    op[i] = (row[i] - M) * 1.25f - lse;
}

// ---------------------------------------------------------------------------
extern "C" void kernel_launch(void* const* d_in, const int* in_sizes, int n_in,
                              void* d_out, int out_size, void* d_ws, size_t ws_size,
                              hipStream_t stream) {
  const float* x    = (const float*)d_in[0];
  const float* hs   = (const float*)d_in[1];
  const float* cs   = (const float*)d_in[2];
  const float* Wh   = (const float*)d_in[3];
  const float* bh   = (const float*)d_in[4];
  const float* Wx0  = (const float*)d_in[5];
  const float* bx0  = (const float*)d_in[6];
  const float* Wx1  = (const float*)d_in[7];
  const float* bx1  = (const float*)d_in[8];
  const float* Wdec = (const float*)d_in[9];
  const float* bdec = (const float*)d_in[10];

  float* out   = (float*)d_out;
  float* logp  = out;                 // 64*32000
  float* houts = out + 2048000;       // 2*64*1024
  float* couts = out + 2179072;       // 2*64*1024

  char* ws = (char*)d_ws;
  ushort* xb     = (ushort*)ws;                              // 4,096,000 B
  ushort* hb     = (ushort*)(ws + 4096000);                  //   262,144 B
  ushort* outb   = (ushort*)(ws + 4358144);                  //   262,144 B
  float*  logits = (float*)(ws + 4620288);                   // 8,192,000 B
  float2* ms     = (float2*)(ws + 12812288);                 //     2,048 B
  float*  zpart  = (float*)(ws + 12814336);
  // zpart slots (1 MiB each): [0,25) x0, [25,27) h0, [27,29) h1,
  // [29,45) layer-1 x-path.  Total 45 MiB; ws total ~57 MiB.

  // 1) fp32 -> bf16 activations (x and both hidden states)
  convert_k<<<2128, 256, 0, stream>>>(x, hs, xb, hb);

  // 2) layer-0 gates + layer-1 h-path: depth-2 prefetch, 2 gates/block
  gates_pf2<<<dim3(16, 29, 2), 256, 0, stream>>>(xb, hb, Wx0, Wh, zpart);

  // 3) layer-0 cell: reduce slots [0, 27)
  lstm_cell_k<<<256, 256, 0, stream>>>(zpart, 27, bx0, bh, cs,
                                       houts, couts, outb);

  // 4) layer-1 x-path gates -> slots [29, 45)
  gates_b16<<<dim3(16, 16), 256, 0, stream>>>(
      outb, Wx1, zpart + (size_t)29 * 262144);

  // 5) layer-1 cell: reduce slots [27, 45)  (h1 partials + x-path)
  lstm_cell_k<<<256, 256, 0, stream>>>(zpart + (size_t)27 * 262144, 18,
                                       bx1, bh + 4096, cs + 65536,
                                       houts + 65536, couts + 65536,
                                       outb + 65536);

  // 6) decoder logits (2000 single-wave blocks)
  gemm_dec<<<2000, 64, 0, stream>>>(outb + 65536, Wdec, bdec, logits);

  // 7) log-softmax, two stages so all CUs participate
  softmax_part1<<<dim3(4, 64), 256, 0, stream>>>(logits, ms);
  softmax_part2<<<dim3(8, 64), 256, 0, stream>>>(logits, ms, logp);
}